// Round 5
// baseline (253.373 us; speedup 1.0000x reference)
//
#include <hip/hip_runtime.h>

typedef __attribute__((ext_vector_type(8))) short bf16x8;
typedef __attribute__((ext_vector_type(4))) float f32x4;
typedef __attribute__((ext_vector_type(2))) unsigned int u32x2;

union UB8 { bf16x8 v; unsigned d[4]; unsigned short u[8]; };

__device__ __forceinline__ float bf2f(unsigned short u) {
  union { unsigned u; float f; } a; a.u = ((unsigned)u) << 16;
  return a.f;
}
// native cast -> v_cvt_pk_bf16_f32 (RNE)
__device__ __forceinline__ unsigned pk2bf(float lo, float hi) {
  union { __bf16 b[2]; unsigned u; } r;
  r.b[0] = (__bf16)lo; r.b[1] = (__bf16)hi;
  return r.u;
}
__device__ __forceinline__ unsigned short f2bf(float f) {  // prep only
  union { float f; unsigned u; } a; a.f = f;
  return (unsigned short)((a.u + 0x7fffu + ((a.u >> 16) & 1u)) >> 16);
}

// ---------------- prep kernel: weights -> bf16, PE table -> f32 ----------------
// ws (u16 view): [0..8191] Wq, [8192..16383] Wk, [16384..32767] Wv, [32768..49151] Wo
// bytes 98304..102399: PE f32 [8][128]
__global__ void prep_kernel(const float* __restrict__ Wq, const float* __restrict__ Wk,
                            const float* __restrict__ Wv, const float* __restrict__ Wo,
                            unsigned short* __restrict__ ws) {
  const int b = blockIdx.x;
  if (b < 192) {
    int i = b * 256 + threadIdx.x;
    float v;
    if (i < 8192) v = Wq[i];
    else if (i < 16384) v = Wk[i - 8192];
    else if (i < 32768) v = Wv[i - 16384];
    else v = Wo[i - 32768];
    ws[i] = f2bf(v);
  } else {
    float* pe = (float*)(ws + 49152);
#pragma unroll
    for (int k = 0; k < 4; ++k) {
      int e = threadIdx.x * 4 + k;        // 0..1023
      int c = e >> 7, col = e & 127;
      float div = expf(-0.14391156831212727f * (float)(col >> 1));
      float ang = (float)c * div;
      pe[e] = (col & 1) ? cosf(ang) : sinf(ang);
    }
  }
}

// ---------------- fused kernel ----------------
// 256 threads (4 waves); 4 batch rows per block (M=32 chunk-rows). 16384 blocks.
// LDS (32768 B):
//   [0..8191]      qkS: Q|K bf16 [32 rows x 256B] swz   (P2 w, P3 r)
//   [8192..24575]  vtS: V^T bf16 [128 vrows x 128B] swz (P2 w, P3 r; 64B used/row)
//   [0..16383]     hbS: h f32 [32 rows x 512B] swz      (P4 w, P5 r; aliases qk+vt)
//   [24576..32767] xcS: xc bf16 [32 rows x 256B] swz    (P1 w; P2 r; P3 ctx w; P4 r)
// VGPR plan: wf 64 + x 16 + pe 8 + bias 4 + temps -> ~120; keep-alive asm pins wf
// so the allocator cannot sink the weight loads into P2 (r4 regression: VGPR=64,
// loads sunk -> serial L2 latency, 251us).
__global__ __launch_bounds__(256, 4)
void wlmha_kernel(const float* __restrict__ x,
                  const unsigned short* __restrict__ wA,
                  const unsigned short* __restrict__ wOb,
                  const float* __restrict__ peG,
                  const float* __restrict__ gamma,
                  const float* __restrict__ beta,
                  const float* __restrict__ relb,
                  float* __restrict__ y_out,
                  float* __restrict__ attn_out)
{
  const int t   = threadIdx.x;
  const int l   = t & 63;
  const int w   = t >> 6;
  const int mr0 = t >> 4;            // 0..15; rows mr0, mr0+16 share (row&7)
  const int cg  = (t & 15) * 8;
  const int sw0 = (mr0 & 7) << 4;
  const int g4  = l >> 4;
  const int qc  = l & 7;
  const long b0 = (long)blockIdx.x * 4;   // batch rows

  __shared__ __align__(16) char smem[32768];
  char* qkS = smem;
  char* vtS = smem + 8192;
  char* hbS = smem;
  char* xcS = smem + 24576;

  // ---------------- P0: issue loads (x first: HBM latency) ----------------
  const float* xb = x + b0 * 1024;
  f32x4 xa0 = *(const f32x4*)(xb + t * 8);
  f32x4 xa1 = *(const f32x4*)(xb + t * 8 + 4);
  f32x4 xb0 = *(const f32x4*)(xb + (t + 256) * 8);
  f32x4 xb1 = *(const f32x4*)(xb + (t + 256) * 8 + 4);

  const float* per = peG + (mr0 & 7) * 128 + cg;
  const f32x4 pe0 = *(const f32x4*)per;
  const f32x4 pe1 = *(const f32x4*)(per + 4);

  // rel-pos bias in regs (no LDS, no barrier)
  float bias[4];
#pragma unroll
  for (int j = 0; j < 4; ++j)
    bias[j] = relb[(w >> 1) * 15 + (g4 & 1) * 4 + j - qc + 7];

  // QKV weight frags (L2-hot) — loaded ONCE, pinned live until P2.
  bf16x8 wf[4][4];
#pragma unroll
  for (int nb = 0; nb < 4; ++nb) {
    const unsigned short* src = wA + (w * 64 + nb * 16 + (l & 15)) * 128 + g4 * 8;
#pragma unroll
    for (int ks = 0; ks < 4; ++ks) wf[nb][ks] = *(const bf16x8*)(src + ks * 32);
  }
  // Pin wf in VGPRs: "+v" makes the asm a writer, so later uses must read the
  // register — the compiler cannot re-load from global inside P2.
#pragma unroll
  for (int nb = 0; nb < 4; ++nb)
#pragma unroll
    for (int ks = 0; ks < 4; ++ks)
      asm volatile("" : "+v"(wf[nb][ks]));

  // ---------------- P1: xc = x + pe -> bf16 xcS (swz) ----------------
  {
    f32x4 a0 = xa0 + pe0, a1 = xa1 + pe1;
    UB8 fr;
    fr.d[0] = pk2bf(a0[0], a0[1]); fr.d[1] = pk2bf(a0[2], a0[3]);
    fr.d[2] = pk2bf(a1[0], a1[1]); fr.d[3] = pk2bf(a1[2], a1[3]);
    *(bf16x8*)(xcS + mr0 * 256 + ((cg * 2) ^ sw0)) = fr.v;
    f32x4 b0v = xb0 + pe0, b1v = xb1 + pe1;
    fr.d[0] = pk2bf(b0v[0], b0v[1]); fr.d[1] = pk2bf(b0v[2], b0v[3]);
    fr.d[2] = pk2bf(b1v[0], b1v[1]); fr.d[3] = pk2bf(b1v[2], b1v[3]);
    *(bf16x8*)(xcS + (mr0 + 16) * 256 + ((cg * 2) ^ sw0)) = fr.v;
  }
  __syncthreads();

  // ---------------- P2: QKV projection via MFMA ----------------
#pragma unroll
  for (int mt = 0; mt < 2; ++mt) {
    bf16x8 xf[4];
    const int row = mt * 16 + (l & 15);
    const int rsw = (row & 7) << 4;
#pragma unroll
    for (int ks = 0; ks < 4; ++ks)
      xf[ks] = *(const bf16x8*)(xcS + row * 256 + ((ks * 64 + g4 * 16) ^ rsw));
    if (w < 2) {
#pragma unroll
      for (int nb = 0; nb < 4; ++nb) {
        f32x4 acc = {0.f, 0.f, 0.f, 0.f};
#pragma unroll
        for (int ks = 0; ks < 4; ++ks)
          acc = __builtin_amdgcn_mfma_f32_16x16x32_bf16(wf[nb][ks], xf[ks], acc, 0, 0, 0);
        u32x2 pk; pk.x = pk2bf(acc[0], acc[1]); pk.y = pk2bf(acc[2], acc[3]);
        const int colb = (w * 128 + nb * 32 + g4 * 8) ^ rsw;
        *(u32x2*)(qkS + row * 256 + colb) = pk;
      }
    } else {
#pragma unroll
      for (int nb = 0; nb < 4; ++nb) {
        f32x4 acc = {0.f, 0.f, 0.f, 0.f};
#pragma unroll
        for (int ks = 0; ks < 4; ++ks)
          acc = __builtin_amdgcn_mfma_f32_16x16x32_bf16(xf[ks], wf[nb][ks], acc, 0, 0, 0);
        const int nv = (w - 2) * 64 + nb * 16 + (l & 15);
        const int rb = mt * 16 + g4 * 4;
        u32x2 pk; pk.x = pk2bf(acc[0], acc[1]); pk.y = pk2bf(acc[2], acc[3]);
        *(u32x2*)(vtS + nv * 128 + ((rb * 2) ^ ((nv & 7) << 4))) = pk;
      }
    }
  }
  // residual snapshot (bf16) before P3 overwrites xcS with ctx
  bf16x8 xcr0 = *(const bf16x8*)(xcS + mr0 * 256 + ((cg * 2) ^ sw0));
  bf16x8 xcr1 = *(const bf16x8*)(xcS + (mr0 + 16) * 256 + ((cg * 2) ^ sw0));
  __syncthreads();

  // ---------------- P3: attention via MFMA (swapped S^T) ----------------
  bf16x8 wof[2][4];
#pragma unroll
  for (int nt = 0; nt < 2; ++nt) {
    const unsigned short* src = wOb + (w * 32 + nt * 16 + (l & 15)) * 128 + g4 * 8;
#pragma unroll
    for (int ks = 0; ks < 4; ++ks) wof[nt][ks] = *(const bf16x8*)(src + ks * 32);
  }
#pragma unroll
  for (int nt = 0; nt < 2; ++nt)
#pragma unroll
    for (int ks = 0; ks < 4; ++ks)
      asm volatile("" : "+v"(wof[nt][ks]));
  {
    const int T = w & 1;
    const int h = w >> 1;
    const bool valid = ((l >> 5) & 1) == ((l >> 3) & 1);
    const int row = T * 16 + (l & 15);
    const int sw = (row & 7) << 4;
    bf16x8 kf = *(const bf16x8*)(qkS + row * 256 + ((128 + h * 64 + g4 * 16) ^ sw));
    bf16x8 qf = *(const bf16x8*)(qkS + row * 256 + ((h * 64 + g4 * 16) ^ sw));
    f32x4 zero = {0.f, 0.f, 0.f, 0.f};
    f32x4 st = __builtin_amdgcn_mfma_f32_16x16x32_bf16(kf, qf, zero, 0, 0, 0);
    float s0[4];
#pragma unroll
    for (int j = 0; j < 4; ++j)
      s0[j] = valid ? st[j] * 0.17677669529663687f + bias[j] : -1e30f;
    float mx = fmaxf(fmaxf(s0[0], s0[1]), fmaxf(s0[2], s0[3]));
    mx = fmaxf(mx, __shfl_xor(mx, 16));
    mx = fmaxf(mx, __shfl_xor(mx, 32));
    float p[4], sum = 0.f;
#pragma unroll
    for (int j = 0; j < 4; ++j) { p[j] = __expf(s0[j] - mx); sum += p[j]; }
    sum += __shfl_xor(sum, 16);
    sum += __shfl_xor(sum, 32);
    const float inv = 1.0f / sum;
#pragma unroll
    for (int j = 0; j < 4; ++j) p[j] *= inv;

    if (valid) {
      float* ap = attn_out + ((b0 + (row >> 3)) * 2 + h) * 64 + qc * 8 + (g4 & 1) * 4;
      f32x4 pv = {p[0], p[1], p[2], p[3]};
      *(f32x4*)ap = pv;
    }

    // P^T B-fragment (k=0..15 real, 16..31 zero)
    const unsigned P0 = pk2bf(p[0], p[1]);
    const unsigned P1 = pk2bf(p[2], p[3]);
    const int sA = (l & 15) + (g4 & 1) * 32;
    UB8 pf;
    pf.d[0] = (unsigned)__shfl((int)P0, sA);
    pf.d[1] = (unsigned)__shfl((int)P1, sA);
    pf.d[2] = (unsigned)__shfl((int)P0, sA + 16);
    pf.d[3] = (unsigned)__shfl((int)P1, sA + 16);
    if (g4 >= 2) { pf.d[0] = 0; pf.d[1] = 0; pf.d[2] = 0; pf.d[3] = 0; }

    // ctx^T = V^T · P^T -> xcS (swz)
#pragma unroll
    for (int vb = 0; vb < 4; ++vb) {
      const int nv = h * 64 + vb * 16 + (l & 15);
      const int kb = (32 * T + 16 * (g4 & 1)) ^ ((nv & 7) << 4);
      bf16x8 vf = *(const bf16x8*)(vtS + nv * 128 + kb);
      f32x4 c = __builtin_amdgcn_mfma_f32_16x16x32_bf16(vf, pf.v, zero, 0, 0, 0);
      u32x2 pk; pk.x = pk2bf(c[0], c[1]); pk.y = pk2bf(c[2], c[3]);
      const int fb = (h * 128 + vb * 32 + g4 * 8) ^ sw;
      *(u32x2*)(xcS + row * 256 + fb) = pk;
    }
  }
  __syncthreads();

  // ---------------- P4: out = ctx @ Wo^T -> hbS f32 (aliases qk+vt) ----------------
  const f32x4 gm0 = *(const f32x4*)(gamma + cg);
  const f32x4 gm1 = *(const f32x4*)(gamma + cg + 4);
  const f32x4 bt0 = *(const f32x4*)(beta + cg);
  const f32x4 bt1 = *(const f32x4*)(beta + cg + 4);
#pragma unroll
  for (int mt = 0; mt < 2; ++mt) {
    bf16x8 cf[4];
    const int row = mt * 16 + (l & 15);
    const int rsw = (row & 7) << 4;
#pragma unroll
    for (int ks = 0; ks < 4; ++ks)
      cf[ks] = *(const bf16x8*)(xcS + row * 256 + ((ks * 64 + g4 * 16) ^ rsw));
#pragma unroll
    for (int nt = 0; nt < 2; ++nt) {
      f32x4 acc = {0.f, 0.f, 0.f, 0.f};
#pragma unroll
      for (int ks = 0; ks < 4; ++ks)
        acc = __builtin_amdgcn_mfma_f32_16x16x32_bf16(wof[nt][ks], cf[ks], acc, 0, 0, 0);
      const int colb = ((w * 32 + nt * 16 + g4 * 4) * 4) ^ rsw;
      *(f32x4*)(hbS + row * 512 + colb) = acc;
    }
  }
  __syncthreads();

  // ---------------- P5: residual(bf16 regs) + LN + y store ----------------
  {
    float* yb = y_out + b0 * 1024;
#pragma unroll
    for (int i = 0; i < 2; ++i) {
      const int m = mr0 + 16 * i;
      const char* hp = hbS + m * 512;
      f32x4 h0 = *(const f32x4*)(hp + ((cg * 4) ^ sw0));
      f32x4 h1 = *(const f32x4*)(hp + ((cg * 4 + 16) ^ sw0));
      UB8 r; r.v = (i == 0) ? xcr0 : xcr1;
      float sum = 0.f, sq = 0.f;
#pragma unroll
      for (int j = 0; j < 4; ++j) {
        h0[j] += bf2f(r.u[j]);
        h1[j] += bf2f(r.u[4 + j]);
        sum += h0[j] + h1[j];
        sq  += h0[j] * h0[j] + h1[j] * h1[j];
      }
#pragma unroll
      for (int d = 1; d < 16; d <<= 1) {
        sum += __shfl_xor(sum, d);
        sq  += __shfl_xor(sq, d);
      }
      const float mu = sum * 0.0078125f;
      const float rs = rsqrtf(sq * 0.0078125f - mu * mu + 1e-5f);
      f32x4 o0, o1;
#pragma unroll
      for (int j = 0; j < 4; ++j) {
        o0[j] = (h0[j] - mu) * rs * gm0[j] + bt0[j];
        o1[j] = (h1[j] - mu) * rs * gm1[j] + bt1[j];
      }
      const int g = t + 256 * i;
      *(f32x4*)(yb + g * 8) = o0;
      *(f32x4*)(yb + g * 8 + 4) = o1;
    }
  }
}

extern "C" void kernel_launch(void* const* d_in, const int* in_sizes, int n_in,
                              void* d_out, int out_size, void* d_ws, size_t ws_size,
                              hipStream_t stream) {
  (void)in_sizes; (void)n_in; (void)out_size; (void)ws_size;
  const float* x    = (const float*)d_in[0];
  const float* Wq   = (const float*)d_in[1];
  const float* Wk   = (const float*)d_in[2];
  const float* Wv   = (const float*)d_in[3];
  const float* Wo   = (const float*)d_in[4];
  const float* gam  = (const float*)d_in[5];
  const float* bet  = (const float*)d_in[6];
  const float* relb = (const float*)d_in[7];
  float* y    = (float*)d_out;
  float* attn = y + (size_t)65536 * 1024;
  unsigned short* ws = (unsigned short*)d_ws;
  const float* peG = (const float*)(ws + 49152);

  hipLaunchKernelGGL(prep_kernel, dim3(193), dim3(256), 0, stream, Wq, Wk, Wv, Wo, ws);
  hipLaunchKernelGGL(wlmha_kernel, dim3(16384), dim3(256), 0, stream,
                     x, ws, ws + 32768, peG, gam, bet, relb, y, attn);
}

// Round 6
// 189.511 us; speedup vs baseline: 1.3370x; 1.3370x over previous
//
#include <hip/hip_runtime.h>

typedef __attribute__((ext_vector_type(8))) short bf16x8;
typedef __attribute__((ext_vector_type(4))) float f32x4;
typedef __attribute__((ext_vector_type(2))) unsigned int u32x2;

union UB8 { bf16x8 v; unsigned d[4]; unsigned short u[8]; };

__device__ __forceinline__ float bf2f(unsigned short u) {
  union { unsigned u; float f; } a; a.u = ((unsigned)u) << 16;
  return a.f;
}
// native cast -> v_cvt_pk_bf16_f32 (RNE)
__device__ __forceinline__ unsigned pk2bf(float lo, float hi) {
  union { __bf16 b[2]; unsigned u; } r;
  r.b[0] = (__bf16)lo; r.b[1] = (__bf16)hi;
  return r.u;
}
__device__ __forceinline__ unsigned short f2bf(float f) {  // prep only
  union { float f; unsigned u; } a; a.f = f;
  return (unsigned short)((a.u + 0x7fffu + ((a.u >> 16) & 1u)) >> 16);
}

// ---------------- prep kernel: weights -> bf16, PE table -> f32 ----------------
// ws (u16 view): [0..8191] Wq, [8192..16383] Wk, [16384..32767] Wv, [32768..49151] Wo
// bytes 98304..102399: PE f32 [8][128]
__global__ void prep_kernel(const float* __restrict__ Wq, const float* __restrict__ Wk,
                            const float* __restrict__ Wv, const float* __restrict__ Wo,
                            unsigned short* __restrict__ ws) {
  const int b = blockIdx.x;
  if (b < 192) {
    int i = b * 256 + threadIdx.x;
    float v;
    if (i < 8192) v = Wq[i];
    else if (i < 16384) v = Wk[i - 8192];
    else if (i < 32768) v = Wv[i - 16384];
    else v = Wo[i - 32768];
    ws[i] = f2bf(v);
  } else {
    float* pe = (float*)(ws + 49152);
#pragma unroll
    for (int k = 0; k < 4; ++k) {
      int e = threadIdx.x * 4 + k;        // 0..1023
      int c = e >> 7, col = e & 127;
      float div = expf(-0.14391156831212727f * (float)(col >> 1));
      float ang = (float)c * div;
      pe[e] = (col & 1) ? cosf(ang) : sinf(ang);
    }
  }
}

// ---------------- fused kernel ----------------
// 512 threads (8 waves); 8 batch rows per block (M=64 chunk-rows). 8192 blocks.
// LDS (49152 B = 48KB -> 3 blocks/CU by LDS):
//   [0..16383]     qkS: Q|K bf16 [64 rows x 256B] swz   (P2 w, P3 r)
//   [16384..32767] vtS: V^T bf16 [128 vrows x 128B] swz (P2 w, P3 r)
//   [0..32767]     hbS: h f32 [64 rows x 512B] swz      (P4 w, P5 r; aliases qk+vt)
//   [32768..49151] xcS: xc bf16 [64 rows x 256B] swz    (P1 w; P2 r; P3 ctx w; P4 r)
// Work split: P2: 8 waves x 32 feats (w0-3: Q|K, w4-7: V->Vt). P3: (T,h)=(w>>1,w&1).
// P4: 8 waves x 16 out-feats. Per-wave wf = 32 VGPR (half of r2) -> fits cap 128.
__global__ __launch_bounds__(512, 4)
void wlmha_kernel(const float* __restrict__ x,
                  const unsigned short* __restrict__ wA,
                  const unsigned short* __restrict__ wOb,
                  const float* __restrict__ peG,
                  const float* __restrict__ gamma,
                  const float* __restrict__ beta,
                  const float* __restrict__ relb,
                  float* __restrict__ y_out,
                  float* __restrict__ attn_out)
{
  const int t   = threadIdx.x;
  const int l   = t & 63;
  const int w   = t >> 6;            // wave 0..7
  const int mr0 = t >> 4;            // 0..31; rows mr0, mr0+32 share (row&7)
  const int cg  = (t & 15) * 8;
  const int sw0 = (mr0 & 7) << 4;
  const int g4  = l >> 4;
  const int qc  = l & 7;
  const long b0 = (long)blockIdx.x * 8;   // batch rows

  __shared__ __align__(16) char smem[49152];
  char* qkS = smem;
  char* vtS = smem + 16384;
  char* hbS = smem;
  char* xcS = smem + 32768;

  // ---------------- P0: issue loads (x first: HBM latency) ----------------
  const float* xb = x + b0 * 1024;
  f32x4 xa0 = *(const f32x4*)(xb + t * 8);
  f32x4 xa1 = *(const f32x4*)(xb + t * 8 + 4);
  f32x4 xb0 = *(const f32x4*)(xb + (t + 512) * 8);
  f32x4 xb1 = *(const f32x4*)(xb + (t + 512) * 8 + 4);

  const float* per = peG + (mr0 & 7) * 128 + cg;
  const f32x4 pe0 = *(const f32x4*)per;
  const f32x4 pe1 = *(const f32x4*)(per + 4);

  // rel-pos bias in regs (P3 role: head h = w&1)
  float bias[4];
#pragma unroll
  for (int j = 0; j < 4; ++j)
    bias[j] = relb[(w & 1) * 15 + (g4 & 1) * 4 + j - qc + 7];

  // QKV weight frags: wave's 32-feature slice. w0-3: rows 0..127 of [Q|K];
  // w4-7: rows 128..255 (V). Loaded once, pinned (32 VGPR/thread).
  bf16x8 wf[2][4];
#pragma unroll
  for (int nb = 0; nb < 2; ++nb) {
    const unsigned short* src = wA + (w * 32 + nb * 16 + (l & 15)) * 128 + g4 * 8;
#pragma unroll
    for (int ks = 0; ks < 4; ++ks) wf[nb][ks] = *(const bf16x8*)(src + ks * 32);
  }
#pragma unroll
  for (int nb = 0; nb < 2; ++nb)
#pragma unroll
    for (int ks = 0; ks < 4; ++ks)
      asm volatile("" : "+v"(wf[nb][ks]));

  // ---------------- P1: xc = x + pe -> bf16 xcS (swz) ----------------
  {
    f32x4 a0 = xa0 + pe0, a1 = xa1 + pe1;
    UB8 fr;
    fr.d[0] = pk2bf(a0[0], a0[1]); fr.d[1] = pk2bf(a0[2], a0[3]);
    fr.d[2] = pk2bf(a1[0], a1[1]); fr.d[3] = pk2bf(a1[2], a1[3]);
    *(bf16x8*)(xcS + mr0 * 256 + ((cg * 2) ^ sw0)) = fr.v;
    f32x4 c0 = xb0 + pe0, c1 = xb1 + pe1;
    fr.d[0] = pk2bf(c0[0], c0[1]); fr.d[1] = pk2bf(c0[2], c0[3]);
    fr.d[2] = pk2bf(c1[0], c1[1]); fr.d[3] = pk2bf(c1[2], c1[3]);
    *(bf16x8*)(xcS + (mr0 + 32) * 256 + ((cg * 2) ^ sw0)) = fr.v;
  }
  __syncthreads();

  // ---------------- P2: QKV projection via MFMA ----------------
#pragma unroll
  for (int mt = 0; mt < 4; ++mt) {
    bf16x8 xf[4];
    const int row = mt * 16 + (l & 15);
    const int rsw = (row & 7) << 4;
#pragma unroll
    for (int ks = 0; ks < 4; ++ks)
      xf[ks] = *(const bf16x8*)(xcS + row * 256 + ((ks * 64 + g4 * 16) ^ rsw));
    if (w < 4) {
      // D = W . xc : lane -> (m=row, features w*32+nb*16+g4*4+j)
#pragma unroll
      for (int nb = 0; nb < 2; ++nb) {
        f32x4 acc = {0.f, 0.f, 0.f, 0.f};
#pragma unroll
        for (int ks = 0; ks < 4; ++ks)
          acc = __builtin_amdgcn_mfma_f32_16x16x32_bf16(wf[nb][ks], xf[ks], acc, 0, 0, 0);
        u32x2 pk; pk.x = pk2bf(acc[0], acc[1]); pk.y = pk2bf(acc[2], acc[3]);
        const int colb = (w * 64 + nb * 32 + g4 * 8) ^ rsw;
        *(u32x2*)(qkS + row * 256 + colb) = pk;
      }
    } else {
      // D = xc . W : lane -> (nv=(w-4)*32+nb*16+(l&15), keys mt*16+g4*4+j)
#pragma unroll
      for (int nb = 0; nb < 2; ++nb) {
        f32x4 acc = {0.f, 0.f, 0.f, 0.f};
#pragma unroll
        for (int ks = 0; ks < 4; ++ks)
          acc = __builtin_amdgcn_mfma_f32_16x16x32_bf16(xf[ks], wf[nb][ks], acc, 0, 0, 0);
        const int nv = (w - 4) * 32 + nb * 16 + (l & 15);
        const int rb = mt * 16 + g4 * 4;
        u32x2 pk; pk.x = pk2bf(acc[0], acc[1]); pk.y = pk2bf(acc[2], acc[3]);
        *(u32x2*)(vtS + nv * 128 + ((rb * 2) ^ ((nv & 7) << 4))) = pk;
      }
    }
  }
  // residual snapshot (bf16) before P3 overwrites xcS with ctx
  bf16x8 xcr0 = *(const bf16x8*)(xcS + mr0 * 256 + ((cg * 2) ^ sw0));
  bf16x8 xcr1 = *(const bf16x8*)(xcS + (mr0 + 32) * 256 + ((cg * 2) ^ sw0));
  __syncthreads();

  // ---------------- P3: attention via MFMA (swapped S^T) ----------------
  bf16x8 wof[4];
  {
    const unsigned short* src = wOb + (w * 16 + (l & 15)) * 128 + g4 * 8;
#pragma unroll
    for (int ks = 0; ks < 4; ++ks) wof[ks] = *(const bf16x8*)(src + ks * 32);
  }
#pragma unroll
  for (int ks = 0; ks < 4; ++ks)
    asm volatile("" : "+v"(wof[ks]));
  {
    const int T = w >> 1;           // 16-row tile 0..3
    const int h = w & 1;            // head
    const bool valid = ((l >> 5) & 1) == ((l >> 3) & 1);
    const int row = T * 16 + (l & 15);
    const int sw = (row & 7) << 4;
    bf16x8 kf = *(const bf16x8*)(qkS + row * 256 + ((128 + h * 64 + g4 * 16) ^ sw));
    bf16x8 qf = *(const bf16x8*)(qkS + row * 256 + ((h * 64 + g4 * 16) ^ sw));
    f32x4 zero = {0.f, 0.f, 0.f, 0.f};
    f32x4 st = __builtin_amdgcn_mfma_f32_16x16x32_bf16(kf, qf, zero, 0, 0, 0);
    float s0[4];
#pragma unroll
    for (int j = 0; j < 4; ++j)
      s0[j] = valid ? st[j] * 0.17677669529663687f + bias[j] : -1e30f;
    float mx = fmaxf(fmaxf(s0[0], s0[1]), fmaxf(s0[2], s0[3]));
    mx = fmaxf(mx, __shfl_xor(mx, 16));
    mx = fmaxf(mx, __shfl_xor(mx, 32));
    float p[4], sum = 0.f;
#pragma unroll
    for (int j = 0; j < 4; ++j) { p[j] = __expf(s0[j] - mx); sum += p[j]; }
    sum += __shfl_xor(sum, 16);
    sum += __shfl_xor(sum, 32);
    const float inv = 1.0f / sum;
#pragma unroll
    for (int j = 0; j < 4; ++j) p[j] *= inv;

    if (valid) {
      float* ap = attn_out + ((b0 + (row >> 3)) * 2 + h) * 64 + qc * 8 + (g4 & 1) * 4;
      f32x4 pv = {p[0], p[1], p[2], p[3]};
      *(f32x4*)ap = pv;
    }

    // P^T B-fragment (k=0..15 real, 16..31 zero)
    const unsigned P0 = pk2bf(p[0], p[1]);
    const unsigned P1 = pk2bf(p[2], p[3]);
    const int sA = (l & 15) + (g4 & 1) * 32;
    UB8 pf;
    pf.d[0] = (unsigned)__shfl((int)P0, sA);
    pf.d[1] = (unsigned)__shfl((int)P1, sA);
    pf.d[2] = (unsigned)__shfl((int)P0, sA + 16);
    pf.d[3] = (unsigned)__shfl((int)P1, sA + 16);
    if (g4 >= 2) { pf.d[0] = 0; pf.d[1] = 0; pf.d[2] = 0; pf.d[3] = 0; }

    // ctx^T = V^T . P^T -> xcS (swz)
#pragma unroll
    for (int vb = 0; vb < 4; ++vb) {
      const int nv = h * 64 + vb * 16 + (l & 15);
      const int kb = (32 * T + 16 * (g4 & 1)) ^ ((nv & 7) << 4);
      bf16x8 vf = *(const bf16x8*)(vtS + nv * 128 + kb);
      f32x4 c = __builtin_amdgcn_mfma_f32_16x16x32_bf16(vf, pf.v, zero, 0, 0, 0);
      u32x2 pk; pk.x = pk2bf(c[0], c[1]); pk.y = pk2bf(c[2], c[3]);
      const int fb = (h * 128 + vb * 32 + g4 * 8) ^ sw;
      *(u32x2*)(xcS + row * 256 + fb) = pk;
    }
  }
  __syncthreads();

  // ---------------- P4: out = ctx @ Wo^T -> hbS f32 (aliases qk+vt) ----------------
  const f32x4 gm0 = *(const f32x4*)(gamma + cg);
  const f32x4 gm1 = *(const f32x4*)(gamma + cg + 4);
  const f32x4 bt0 = *(const f32x4*)(beta + cg);
  const f32x4 bt1 = *(const f32x4*)(beta + cg + 4);
#pragma unroll
  for (int mt = 0; mt < 4; ++mt) {
    bf16x8 cf[4];
    const int row = mt * 16 + (l & 15);
    const int rsw = (row & 7) << 4;
#pragma unroll
    for (int ks = 0; ks < 4; ++ks)
      cf[ks] = *(const bf16x8*)(xcS + row * 256 + ((ks * 64 + g4 * 16) ^ rsw));
    f32x4 acc = {0.f, 0.f, 0.f, 0.f};
#pragma unroll
    for (int ks = 0; ks < 4; ++ks)
      acc = __builtin_amdgcn_mfma_f32_16x16x32_bf16(wof[ks], cf[ks], acc, 0, 0, 0);
    // lane: out features w*16 + g4*4 + j for row m -> f32x4
    const int colb = ((w * 16 + g4 * 4) * 4) ^ rsw;
    *(f32x4*)(hbS + row * 512 + colb) = acc;
  }
  __syncthreads();

  // ---------------- P5: residual(bf16 regs) + LN + y store ----------------
  {
    float* yb = y_out + b0 * 1024;
#pragma unroll
    for (int i = 0; i < 2; ++i) {
      const int m = mr0 + 32 * i;
      const char* hp = hbS + m * 512;
      f32x4 h0 = *(const f32x4*)(hp + ((cg * 4) ^ sw0));
      f32x4 h1 = *(const f32x4*)(hp + ((cg * 4 + 16) ^ sw0));
      UB8 r; r.v = (i == 0) ? xcr0 : xcr1;
      float sum = 0.f, sq = 0.f;
#pragma unroll
      for (int j = 0; j < 4; ++j) {
        h0[j] += bf2f(r.u[j]);
        h1[j] += bf2f(r.u[4 + j]);
        sum += h0[j] + h1[j];
        sq  += h0[j] * h0[j] + h1[j] * h1[j];
      }
#pragma unroll
      for (int d = 1; d < 16; d <<= 1) {
        sum += __shfl_xor(sum, d);
        sq  += __shfl_xor(sq, d);
      }
      const float mu = sum * 0.0078125f;
      const float rs = rsqrtf(sq * 0.0078125f - mu * mu + 1e-5f);
      f32x4 o0, o1;
#pragma unroll
      for (int j = 0; j < 4; ++j) {
        o0[j] = (h0[j] - mu) * rs * gm0[j] + bt0[j];
        o1[j] = (h1[j] - mu) * rs * gm1[j] + bt1[j];
      }
      const int g = t + 512 * i;
      *(f32x4*)(yb + g * 8) = o0;
      *(f32x4*)(yb + g * 8 + 4) = o1;
    }
  }
}

extern "C" void kernel_launch(void* const* d_in, const int* in_sizes, int n_in,
                              void* d_out, int out_size, void* d_ws, size_t ws_size,
                              hipStream_t stream) {
  (void)in_sizes; (void)n_in; (void)out_size; (void)ws_size;
  const float* x    = (const float*)d_in[0];
  const float* Wq   = (const float*)d_in[1];
  const float* Wk   = (const float*)d_in[2];
  const float* Wv   = (const float*)d_in[3];
  const float* Wo   = (const float*)d_in[4];
  const float* gam  = (const float*)d_in[5];
  const float* bet  = (const float*)d_in[6];
  const float* relb = (const float*)d_in[7];
  float* y    = (float*)d_out;
  float* attn = y + (size_t)65536 * 1024;
  unsigned short* ws = (unsigned short*)d_ws;
  const float* peG = (const float*)(ws + 49152);

  hipLaunchKernelGGL(prep_kernel, dim3(193), dim3(256), 0, stream, Wq, Wk, Wv, Wo, ws);
  hipLaunchKernelGGL(wlmha_kernel, dim3(8192), dim3(512), 0, stream,
                     x, ws, ws + 32768, peG, gam, bet, relb, y, attn);
}